// Round 8
// baseline (287.219 us; speedup 1.0000x reference)
//
#include <hip/hip_runtime.h>
#include <math.h>

#define EPSV 1e-6f
#define NTOK 8192
#define NE   16384
#define DIM  256

using short8 = __attribute__((ext_vector_type(8))) short;
using f32x4v = __attribute__((ext_vector_type(4))) float;

__device__ __forceinline__ unsigned short f2bf(float v) {
    unsigned int u = __float_as_uint(v);
    u += 0x7fffu + ((u >> 16) & 1u);   // RNE
    return (unsigned short)(u >> 16);
}
__device__ __forceinline__ float bf2f(unsigned short h) {
    return __uint_as_float(((unsigned int)h) << 16);
}

__device__ __forceinline__ void gload_lds16(const void* g, void* s) {
    __builtin_amdgcn_global_load_lds(
        (const __attribute__((address_space(1))) void*)g,
        (__attribute__((address_space(3))) void*)s, 16, 0, 0);
}

// split 8 consecutive fp32 into bf16 hi/lo fragments
__device__ __forceinline__ void split8(const float4 a, const float4 b,
                                       short8& h, short8& l) {
    float f[8] = {a.x, a.y, a.z, a.w, b.x, b.y, b.z, b.w};
#pragma unroll
    for (int j = 0; j < 8; ++j) {
        unsigned short hh = f2bf(f[j]);
        h[j] = (short)hh;
        l[j] = (short)f2bf(f[j] - bf2f(hh));
    }
}

// ---------------------------------------------------------------- F0:
// blocks [0,128): z transpose + bf16 split + per-token sz (fp64).
// blocks [128,384): emb = cb @ W.T (4-term bf16x2 MFMA, W split in-register
// from fp32 — no wh/wl dependency) + emb bf16 split + se partials.
__global__ __launch_bounds__(256, 2) void f0_pre(
    const float* __restrict__ zin, float* __restrict__ z_flat,
    unsigned short* __restrict__ zh, unsigned short* __restrict__ zl,
    float* __restrict__ sz, const float* __restrict__ cb,
    const float* __restrict__ Wm, float* __restrict__ emb,
    unsigned short* __restrict__ eh, unsigned short* __restrict__ el,
    float* __restrict__ se0, float* __restrict__ se1) {
    __shared__ char smemC[65536];
    const int tid = threadIdx.x;

    if (blockIdx.x < 128) {            // ================= z path
        float (*tile)[65] = (float(*)[65])smemC;
        const int bid = blockIdx.x;
        const int yx0 = (bid & 15) * 64, b = bid >> 4;
        const int sub = tid >> 6, ln = tid & 63;
        double dacc[16];
#pragma unroll
        for (int j = 0; j < 16; ++j) dacc[j] = 0.0;

        for (int cc = 0; cc < 4; ++cc) {
            const int c0 = cc * 64;
            __syncthreads();
#pragma unroll
            for (int j = 0; j < 16; ++j) {
                int cl = j * 4 + sub;
                tile[cl][ln] = zin[((size_t)(b * 256 + c0 + cl) << 10) + yx0 + ln];
            }
            __syncthreads();
#pragma unroll
            for (int j = 0; j < 16; ++j) {
                int tl = j * 4 + sub;
                float v = tile[ln][tl];
                size_t o = (size_t)(b * 1024 + yx0 + tl) * 256 + c0 + ln;
                z_flat[o] = v;
                unsigned short h = f2bf(v);
                zh[o] = h;
                zl[o] = f2bf(v - bf2f(h));
                dacc[j] += (double)v * v;
            }
        }
#pragma unroll
        for (int j = 0; j < 16; ++j) {
            double s = dacc[j];
#pragma unroll
            for (int m = 1; m < 64; m <<= 1) s += __shfl_xor(s, m);
            if (ln == 0) sz[b * 1024 + yx0 + j * 4 + sub] = (float)s;
        }
        return;
    }

    // ================= emb GEMM path
    const int bid2 = blockIdx.x - 128;
    const int w = tid >> 6, lane = tid & 63;
    const int quad = lane >> 4, lr = lane & 15;
    const int wr = w & 1, wc = w >> 1;
    const int n0 = (bid2 & 127) * 128, c0 = (bid2 >> 7) * 128;

    f32x4v acc[4][4];
#pragma unroll
    for (int mt = 0; mt < 4; ++mt)
#pragma unroll
        for (int nt = 0; nt < 4; ++nt)
            acc[mt][nt] = (f32x4v){0.f, 0.f, 0.f, 0.f};

    for (int kc = 0; kc < 4; ++kc) {
        __syncthreads();
#pragma unroll
        for (int i = 0; i < 16; ++i) {
            int s = i * 4 + w;           // wave-uniform segment 0..63
            int u = s * 64 + lane;       // global unit 0..4095
            const void* g;
            if (s < 32) {                // cbS: [kg(16)][row(128)] fp32x4
                int kg = u >> 7, row = u & 127;
                g = cb + (size_t)(n0 + row) * 256 + kc * 64 + kg * 4;
            } else {                     // wS fp32: [kg(16)][row(128)]
                int u1 = u - 2048;
                int kg = u1 >> 7, row = u1 & 127;
                g = Wm + (size_t)(c0 + row) * 256 + kc * 64 + kg * 4;
            }
            gload_lds16(g, smemC + ((size_t)u << 4));
        }
        __syncthreads();
#pragma unroll
        for (int ks = 0; ks < 2; ++ks) {
            short8 Ah[4], Al[4], Bh[4], Bl[4];
#pragma unroll
            for (int mt = 0; mt < 4; ++mt) {
                int m = wr * 64 + mt * 16 + lr;
                int kg2 = ks * 8 + quad * 2;
                float4 f0 = *(const float4*)(smemC + (((size_t)kg2 * 128 + m) << 4));
                float4 f1 = *(const float4*)(smemC + ((((size_t)kg2 + 1) * 128 + m) << 4));
                split8(f0, f1, Ah[mt], Al[mt]);
            }
#pragma unroll
            for (int nt = 0; nt < 4; ++nt) {
                int n = wc * 64 + nt * 16 + lr;
                int kg2 = ks * 8 + quad * 2;
                float4 g0 = *(const float4*)(smemC + (((size_t)(2048 + kg2 * 128 + n)) << 4));
                float4 g1 = *(const float4*)(smemC + (((size_t)(2048 + (kg2 + 1) * 128 + n)) << 4));
                split8(g0, g1, Bh[nt], Bl[nt]);
            }
#pragma unroll
            for (int mt = 0; mt < 4; ++mt)
#pragma unroll
                for (int nt = 0; nt < 4; ++nt) {
                    f32x4v a = acc[mt][nt];
                    a = __builtin_amdgcn_mfma_f32_16x16x32_bf16(Ah[mt], Bh[nt], a, 0, 0, 0);
                    a = __builtin_amdgcn_mfma_f32_16x16x32_bf16(Ah[mt], Bl[nt], a, 0, 0, 0);
                    a = __builtin_amdgcn_mfma_f32_16x16x32_bf16(Al[mt], Bh[nt], a, 0, 0, 0);
                    a = __builtin_amdgcn_mfma_f32_16x16x32_bf16(Al[mt], Bl[nt], a, 0, 0, 0);
                    acc[mt][nt] = a;
                }
        }
    }
#pragma unroll
    for (int mt = 0; mt < 4; ++mt)
#pragma unroll
        for (int rr = 0; rr < 4; ++rr) {
            int row = n0 + wr * 64 + mt * 16 + quad * 4 + rr;
#pragma unroll
            for (int nt = 0; nt < 4; ++nt) {
                int col = c0 + wc * 64 + nt * 16 + lr;
                size_t o = (size_t)row * 256 + col;
                float v = acc[mt][nt][rr];
                emb[o] = v;
                unsigned short h = f2bf(v);
                eh[o] = h;
                el[o] = f2bf(v - bf2f(h));
            }
        }
    // ---- se partial over this block's 128 cols
    __syncthreads();
    float* sblk = (float*)smemC;       // [2][128]
#pragma unroll
    for (int mt = 0; mt < 4; ++mt)
#pragma unroll
        for (int rr = 0; rr < 4; ++rr) {
            float s = 0.f;
#pragma unroll
            for (int nt = 0; nt < 4; ++nt) {
                float v = acc[mt][nt][rr];
                s = fmaf(v, v, s);
            }
#pragma unroll
            for (int st = 1; st < 16; st <<= 1) s += __shfl_xor(s, st);
            if (lr == 0)
                sblk[wc * 128 + wr * 64 + mt * 16 + quad * 4 + rr] = s;
        }
    __syncthreads();
    if (tid < 128) {
        float* sep = ((bid2 >> 7) == 0) ? se0 : se1;
        sep[n0 + tid] = sblk[tid] + sblk[128 + tid];
    }
}

// ---------------------------------------------------------------- K1:
// Fused bf16x2 (3-term) 16x16x32-MFMA GEMM + argmin (R7 body).
// NEW: LDS layout [fmt][kg(32)][col(32)] -> all 32 B-reads per chunk are
// ds_read_b128 off ONE base VGPR with compile-time offsets
// (fmt*16384 + ks*2048 + nt*256); zero per-read VALU. Staging stays fully
// coalesced (one 128B line = 8 consecutive lanes of one inst); B-reads are
// 2-lanes/bank per phase = free.
__global__ __launch_bounds__(256, 2) void k1_dist_argmin(
    const unsigned short* __restrict__ zh, const unsigned short* __restrict__ zl,
    const unsigned short* __restrict__ eh, const unsigned short* __restrict__ el,
    const float* __restrict__ sz, const float* __restrict__ se0,
    const float* __restrict__ se1, float* __restrict__ pval,
    int* __restrict__ pidx) {
    __shared__ char smem[65536];       // 2 x 32 KB double buffer
    const int tid = threadIdx.x;
    const int w = tid >> 6, lane = tid & 63;
    const int quad = lane >> 4, lr = lane & 15;
    const int tokBase = blockIdx.x * 128;
    const int rowBase = tokBase + w * 32;
    const int slab = blockIdx.y;
    const int slabBase = slab * 2048;

    // A fragments resident for the whole kernel (128 VGPRs)
    short8 Ah[2][8], Al[2][8];
#pragma unroll
    for (int mt = 0; mt < 2; ++mt)
#pragma unroll
        for (int ks = 0; ks < 8; ++ks) {
            size_t o = (size_t)(rowBase + mt * 16 + lr) * 256 + ks * 32 + quad * 8;
            Ah[mt][ks] = *(const short8*)(zh + o);
            Al[mt][ks] = *(const short8*)(zl + o);
        }

    float szr[2][4];
#pragma unroll
    for (int mt = 0; mt < 2; ++mt)
#pragma unroll
        for (int rr = 0; rr < 4; ++rr)
            szr[mt][rr] = sz[rowBase + mt * 16 + quad * 4 + rr];

    float minv[2][4];
    int mini[2][4];
#pragma unroll
    for (int mt = 0; mt < 2; ++mt)
#pragma unroll
        for (int rr = 0; rr < 4; ++rr) {
            minv[mt][rr] = INFINITY;
            mini[mt][rr] = 0;
        }

    // stage chunk `ch` into buffer `buf`; unit u = fmt*1024 + kg*32 + col
    auto stage = [&](int buf, int ch) {
        const int colBase = slabBase + ch * 32;
#pragma unroll
        for (int i = 0; i < 8; ++i) {
            int u = i * 256 + tid;      // 0..2047
            int fmt = u >> 10;          // wave-uniform per i
            int u1 = u & 1023;
            int kg = u1 >> 5, col = u1 & 31;
            const unsigned short* g =
                (fmt ? el : eh) + (size_t)(colBase + col) * 256 + kg * 8;
            gload_lds16(g, smem + buf * 32768 + ((size_t)u << 4));
        }
    };

    stage(0, 0);
    __syncthreads();

    // single lane-dependent B base: quad*512 + lr*16
    const int bOff = quad * 512 + lr * 16;

    for (int ch = 0; ch < 64; ++ch) {
        const int cur = ch & 1;
        if (ch + 1 < 64) stage(cur ^ 1, ch + 1);  // async prefetch

        // hoist se loads under the MFMA burst
        const int colg0 = slabBase + ch * 32 + lr;
        const int colg1 = colg0 + 16;
        const float sec0 = se0[colg0] + se1[colg0];
        const float sec1 = se0[colg1] + se1[colg1];

        f32x4v acc[2][2];
#pragma unroll
        for (int mt = 0; mt < 2; ++mt)
#pragma unroll
            for (int nt = 0; nt < 2; ++nt)
                acc[mt][nt] = (f32x4v){0.f, 0.f, 0.f, 0.f};

        const char* p0 = smem + cur * 32768 + bOff;
#pragma unroll
        for (int ks = 0; ks < 8; ++ks) {
            short8 Bh[2], Bl[2];
#pragma unroll
            for (int nt = 0; nt < 2; ++nt) {
                Bh[nt] = *(const short8*)(p0 + (ks * 2048 + nt * 256));
                Bl[nt] = *(const short8*)(p0 + (16384 + ks * 2048 + nt * 256));
            }
#pragma unroll
            for (int mt = 0; mt < 2; ++mt)
#pragma unroll
                for (int nt = 0; nt < 2; ++nt) {
                    f32x4v a = acc[mt][nt];
                    a = __builtin_amdgcn_mfma_f32_16x16x32_bf16(Ah[mt][ks], Bh[nt], a, 0, 0, 0);
                    a = __builtin_amdgcn_mfma_f32_16x16x32_bf16(Ah[mt][ks], Bl[nt], a, 0, 0, 0);
                    a = __builtin_amdgcn_mfma_f32_16x16x32_bf16(Al[mt][ks], Bh[nt], a, 0, 0, 0);
                    acc[mt][nt] = a;
                }
        }

        // d = fma(-2, dot, fl(sz+se)) == fl(fl(sz+se) - 2*dot) exactly
        const int colBase = slabBase + ch * 32;
#pragma unroll
        for (int nt = 0; nt < 2; ++nt) {
            const int colg = colBase + nt * 16 + lr;
            const float sec = nt ? sec1 : sec0;
#pragma unroll
            for (int mt = 0; mt < 2; ++mt)
#pragma unroll
                for (int rr = 0; rr < 4; ++rr) {
                    float szse = __fadd_rn(szr[mt][rr], sec);
                    float d = fmaf(-2.0f, acc[mt][nt][rr], szse);
                    if (d < minv[mt][rr]) {   // strict <: first index wins
                        minv[mt][rr] = d;
                        mini[mt][rr] = colg;
                    }
                }
        }
        __syncthreads();   // prefetch landed + cur consumed
    }

    // reduce across the 16 lanes (lr) that share each output row
#pragma unroll
    for (int st = 1; st < 16; st <<= 1) {
#pragma unroll
        for (int mt = 0; mt < 2; ++mt)
#pragma unroll
            for (int rr = 0; rr < 4; ++rr) {
                float ov = __shfl_xor(minv[mt][rr], st);
                int oi = __shfl_xor(mini[mt][rr], st);
                if (ov < minv[mt][rr] ||
                    (ov == minv[mt][rr] && oi < mini[mt][rr])) {
                    minv[mt][rr] = ov;
                    mini[mt][rr] = oi;
                }
            }
    }
    if (lr == 0) {
#pragma unroll
        for (int mt = 0; mt < 2; ++mt)
#pragma unroll
            for (int rr = 0; rr < 4; ++rr) {
                int row = rowBase + mt * 16 + quad * 4 + rr;
                pval[(size_t)row * 8 + slab] = minv[mt][rr];
                pidx[(size_t)row * 8 + slab] = mini[mt][rr];
            }
    }
}

// ---------------------------------------------------------------- K3a:
// per-token: reduce 8 slab partials -> final index; rotation scalars;
// per-block loss partial. Reuses sz / se (one reduction instead of four).
__global__ __launch_bounds__(256) void k3a_token(
    const float* __restrict__ z_flat, const float* __restrict__ emb,
    const float* __restrict__ pval, const int* __restrict__ pidx,
    const float* __restrict__ sz, const float* __restrict__ se0,
    const float* __restrict__ se1, float* __restrict__ alpha,
    float* __restrict__ beta, int* __restrict__ idxf,
    float* __restrict__ out, float* __restrict__ lpart) {
    __shared__ float red[4];
    const int w = threadIdx.x >> 6, lane = threadIdx.x & 63;
    const int t = blockIdx.x * 4 + w;

    float bv = INFINITY;
    int bi = 0x7fffffff;
    if (lane < 8) {
        bv = pval[(size_t)t * 8 + lane];
        bi = pidx[(size_t)t * 8 + lane];
    }
#pragma unroll
    for (int st = 1; st < 8; st <<= 1) {
        float ov = __shfl_xor(bv, st);
        int oi = __shfl_xor(bi, st);
        if (ov < bv || (ov == bv && oi < bi)) { bv = ov; bi = oi; }
    }
    const int best = __shfl(bi, 0);

    const float4 zv = *(const float4*)(z_flat + (size_t)t * 256 + lane * 4);
    const float4 ev = *(const float4*)(emb + (size_t)best * 256 + lane * 4);
    float zes = zv.x * ev.x + zv.y * ev.y + zv.z * ev.z + zv.w * ev.w;
#pragma unroll
    for (int m = 1; m < 64; m <<= 1) zes += __shfl_xor(zes, m);

    if (lane == 0) {
        const float szs = sz[t];
        const float ses = se0[best] + se1[best];
        const float sqs = szs + ses - 2.0f * zes;    // loss term (loose tol)
        float ns = sqrtf(szs), nt = sqrtf(ses);
        float inv_s = 1.0f / (ns + EPSV);
        float inv_t = 1.0f / (nt + EPSV);
        float s2 = szs * inv_s;                      // z . u
        float su = szs * inv_s * inv_s;
        float sq = ses * inv_t * inv_t;
        float uq = zes * inv_s * inv_t;
        float nw = sqrtf(su + sq + 2.0f * uq);
        float inv_w = 1.0f / (nw + EPSV);
        float s1 = (s2 + zes * inv_t) * inv_w;       // z . w_
        float scale = nt * inv_s;
        float a = scale * (1.0f - 2.0f * s1 * inv_w * inv_s);
        float bb = scale * inv_t * 2.0f * (s2 - s1 * inv_w);
        alpha[t] = a;
        beta[t] = bb;
        idxf[t] = best;
        out[2097153 + t] = (float)best;
        red[w] = sqs;
    }
    __syncthreads();
    if (threadIdx.x == 0)
        lpart[blockIdx.x] = red[0] + red[1] + red[2] + red[3];
}

// ---------------------------------------------------------------- K3b:
// Tiled z_q: coalesced emb-row gathers + LDS transpose + coalesced writes.
// Grid (128, 4): x = 64-token tile, y = 64-channel tile.
// Block (0,0) also reduces the loss.
__global__ __launch_bounds__(256) void k3b_zq(
    const float* __restrict__ z_flat, const float* __restrict__ emb,
    const float* __restrict__ alpha, const float* __restrict__ beta,
    const int* __restrict__ idxf, const float* __restrict__ lpart,
    float* __restrict__ out) {
    __shared__ float Q[64][65];
    __shared__ float Asm[64], Bsm[64];
    __shared__ int Ism[64];
    const int tid = threadIdx.x;
    const int t0 = blockIdx.x * 64;
    const int c0 = blockIdx.y * 64;

    if (blockIdx.x == 0 && blockIdx.y == 0) {   // ---- loss reduction
        __shared__ float red[4];
        float s = 0.0f;
        for (int i = tid; i < 2048; i += 256) s += lpart[i];
#pragma unroll
        for (int m = 1; m < 64; m <<= 1) s += __shfl_xor(s, m);
        if ((tid & 63) == 0) red[tid >> 6] = s;
        __syncthreads();
        if (tid == 0)
            out[2097152] = 1.25f * (red[0] + red[1] + red[2] + red[3]) *
                           (1.0f / 2097152.0f);
    }

    if (tid < 64) {
        Asm[tid] = alpha[t0 + tid];
        Bsm[tid] = beta[t0 + tid];
        Ism[tid] = idxf[t0 + tid];
    }
    __syncthreads();

    const int sub = tid >> 6, ln = tid & 63;
#pragma unroll
    for (int j = 0; j < 16; ++j) {
        int tl = j * 4 + sub;
        float e = emb[(size_t)Ism[tl] * 256 + c0 + ln];
        float zv = z_flat[(size_t)(t0 + tl) * 256 + c0 + ln];
        Q[tl][ln] = Asm[tl] * zv + Bsm[tl] * e;
    }
    __syncthreads();
    const int b = t0 >> 10, yx0 = t0 & 1023;
#pragma unroll
    for (int j = 0; j < 16; ++j) {
        int cl = j * 4 + sub;
        out[((size_t)(b * 256 + c0 + cl) << 10) + yx0 + ln] = Q[ln][cl];
    }
}

// ----------------------------------------------------------------
extern "C" void kernel_launch(void* const* d_in, const int* in_sizes, int n_in,
                              void* d_out, int out_size, void* d_ws,
                              size_t ws_size, hipStream_t stream) {
    (void)in_sizes; (void)n_in; (void)out_size; (void)ws_size;
    const float* zin = (const float*)d_in[0];
    const float* cb  = (const float*)d_in[1];
    const float* Wm  = (const float*)d_in[2];
    float* out = (float*)d_out;
    char* ws = (char*)d_ws;

    float*          z_flat = (float*)(ws + 0);                     //  8 MB
    unsigned short* zh     = (unsigned short*)(ws + 8388608);      //  4 MB
    unsigned short* zl     = (unsigned short*)(ws + 12582912);     //  4 MB
    float*          emb    = (float*)(ws + 16777216);              // 16 MB
    unsigned short* eh     = (unsigned short*)(ws + 33554432);     //  8 MB
    unsigned short* el     = (unsigned short*)(ws + 41943040);     //  8 MB
    float*          sz     = (float*)(ws + 50331648);              // 32 KB
    float*          se0    = (float*)(ws + 50364416);              // 64 KB
    float*          se1    = (float*)(ws + 50429952);              // 64 KB
    float*          pval   = (float*)(ws + 50495488);              // 256 KB
    int*            pidx   = (int*)(ws + 50757632);                // 256 KB
    float*          alpha  = (float*)(ws + 51019776);              // 32 KB
    float*          beta   = (float*)(ws + 51052544);              // 32 KB
    int*            idxf   = (int*)(ws + 51085312);                // 32 KB
    float*          lpart  = (float*)(ws + 51118080);              //  8 KB

    f0_pre<<<384, 256, 0, stream>>>(zin, z_flat, zh, zl, sz, cb, Wm,
                                    emb, eh, el, se0, se1);
    k1_dist_argmin<<<dim3(64, 8), 256, 0, stream>>>(zh, zl, eh, el, sz,
                                                    se0, se1, pval, pidx);
    k3a_token<<<2048, 256, 0, stream>>>(z_flat, emb, pval, pidx, sz, se0, se1,
                                        alpha, beta, idxf, out, lpart);
    k3b_zq<<<dim3(128, 4), 256, 0, stream>>>(z_flat, emb, alpha, beta, idxf,
                                             lpart, out);
}

// Round 9
// 287.077 us; speedup vs baseline: 1.0005x; 1.0005x over previous
//
#include <hip/hip_runtime.h>
#include <math.h>

#define EPSV 1e-6f
#define NTOK 8192
#define NE   16384
#define DIM  256

using short8 = __attribute__((ext_vector_type(8))) short;
using f32x4v = __attribute__((ext_vector_type(4))) float;

__device__ __forceinline__ unsigned short f2bf(float v) {
    unsigned int u = __float_as_uint(v);
    u += 0x7fffu + ((u >> 16) & 1u);   // RNE
    return (unsigned short)(u >> 16);
}
__device__ __forceinline__ float bf2f(unsigned short h) {
    return __uint_as_float(((unsigned int)h) << 16);
}

__device__ __forceinline__ void gload_lds16(const void* g, void* s) {
    __builtin_amdgcn_global_load_lds(
        (const __attribute__((address_space(1))) void*)g,
        (__attribute__((address_space(3))) void*)s, 16, 0, 0);
}

// split 8 consecutive fp32 into bf16 hi/lo fragments
__device__ __forceinline__ void split8(const float4 a, const float4 b,
                                       short8& h, short8& l) {
    float f[8] = {a.x, a.y, a.z, a.w, b.x, b.y, b.z, b.w};
#pragma unroll
    for (int j = 0; j < 8; ++j) {
        unsigned short hh = f2bf(f[j]);
        h[j] = (short)hh;
        l[j] = (short)f2bf(f[j] - bf2f(hh));
    }
}

// ---------------------------------------------------------------- F0:
// blocks [0,128): z transpose + bf16 split + per-token sz (fp64).
// blocks [128,384): emb = cb @ W.T (4-term bf16x2 MFMA, W split in-register
// from fp32) + emb bf16 split + se partials.
__global__ __launch_bounds__(256, 2) void f0_pre(
    const float* __restrict__ zin, float* __restrict__ z_flat,
    unsigned short* __restrict__ zh, unsigned short* __restrict__ zl,
    float* __restrict__ sz, const float* __restrict__ cb,
    const float* __restrict__ Wm, float* __restrict__ emb,
    unsigned short* __restrict__ eh, unsigned short* __restrict__ el,
    float* __restrict__ se0, float* __restrict__ se1) {
    __shared__ char smemC[65536];
    const int tid = threadIdx.x;

    if (blockIdx.x < 128) {            // ================= z path
        float (*tile)[65] = (float(*)[65])smemC;
        const int bid = blockIdx.x;
        const int yx0 = (bid & 15) * 64, b = bid >> 4;
        const int sub = tid >> 6, ln = tid & 63;
        double dacc[16];
#pragma unroll
        for (int j = 0; j < 16; ++j) dacc[j] = 0.0;

        for (int cc = 0; cc < 4; ++cc) {
            const int c0 = cc * 64;
            __syncthreads();
#pragma unroll
            for (int j = 0; j < 16; ++j) {
                int cl = j * 4 + sub;
                tile[cl][ln] = zin[((size_t)(b * 256 + c0 + cl) << 10) + yx0 + ln];
            }
            __syncthreads();
#pragma unroll
            for (int j = 0; j < 16; ++j) {
                int tl = j * 4 + sub;
                float v = tile[ln][tl];
                size_t o = (size_t)(b * 1024 + yx0 + tl) * 256 + c0 + ln;
                z_flat[o] = v;
                unsigned short h = f2bf(v);
                zh[o] = h;
                zl[o] = f2bf(v - bf2f(h));
                dacc[j] += (double)v * v;
            }
        }
#pragma unroll
        for (int j = 0; j < 16; ++j) {
            double s = dacc[j];
#pragma unroll
            for (int m = 1; m < 64; m <<= 1) s += __shfl_xor(s, m);
            if (ln == 0) sz[b * 1024 + yx0 + j * 4 + sub] = (float)s;
        }
        return;
    }

    // ================= emb GEMM path
    const int bid2 = blockIdx.x - 128;
    const int w = tid >> 6, lane = tid & 63;
    const int quad = lane >> 4, lr = lane & 15;
    const int wr = w & 1, wc = w >> 1;
    const int n0 = (bid2 & 127) * 128, c0 = (bid2 >> 7) * 128;

    f32x4v acc[4][4];
#pragma unroll
    for (int mt = 0; mt < 4; ++mt)
#pragma unroll
        for (int nt = 0; nt < 4; ++nt)
            acc[mt][nt] = (f32x4v){0.f, 0.f, 0.f, 0.f};

    for (int kc = 0; kc < 4; ++kc) {
        __syncthreads();
#pragma unroll
        for (int i = 0; i < 16; ++i) {
            int s = i * 4 + w;           // wave-uniform segment 0..63
            int u = s * 64 + lane;       // global unit 0..4095
            const void* g;
            if (s < 32) {                // cbS: [kg(16)][row(128)] fp32x4
                int kg = u >> 7, row = u & 127;
                g = cb + (size_t)(n0 + row) * 256 + kc * 64 + kg * 4;
            } else {                     // wS fp32: [kg(16)][row(128)]
                int u1 = u - 2048;
                int kg = u1 >> 7, row = u1 & 127;
                g = Wm + (size_t)(c0 + row) * 256 + kc * 64 + kg * 4;
            }
            gload_lds16(g, smemC + ((size_t)u << 4));
        }
        __syncthreads();
#pragma unroll
        for (int ks = 0; ks < 2; ++ks) {
            short8 Ah[4], Al[4], Bh[4], Bl[4];
#pragma unroll
            for (int mt = 0; mt < 4; ++mt) {
                int m = wr * 64 + mt * 16 + lr;
                int kg2 = ks * 8 + quad * 2;
                float4 f0 = *(const float4*)(smemC + (((size_t)kg2 * 128 + m) << 4));
                float4 f1 = *(const float4*)(smemC + ((((size_t)kg2 + 1) * 128 + m) << 4));
                split8(f0, f1, Ah[mt], Al[mt]);
            }
#pragma unroll
            for (int nt = 0; nt < 4; ++nt) {
                int n = wc * 64 + nt * 16 + lr;
                int kg2 = ks * 8 + quad * 2;
                float4 g0 = *(const float4*)(smemC + (((size_t)(2048 + kg2 * 128 + n)) << 4));
                float4 g1 = *(const float4*)(smemC + (((size_t)(2048 + (kg2 + 1) * 128 + n)) << 4));
                split8(g0, g1, Bh[nt], Bl[nt]);
            }
#pragma unroll
            for (int mt = 0; mt < 4; ++mt)
#pragma unroll
                for (int nt = 0; nt < 4; ++nt) {
                    f32x4v a = acc[mt][nt];
                    a = __builtin_amdgcn_mfma_f32_16x16x32_bf16(Ah[mt], Bh[nt], a, 0, 0, 0);
                    a = __builtin_amdgcn_mfma_f32_16x16x32_bf16(Ah[mt], Bl[nt], a, 0, 0, 0);
                    a = __builtin_amdgcn_mfma_f32_16x16x32_bf16(Al[mt], Bh[nt], a, 0, 0, 0);
                    a = __builtin_amdgcn_mfma_f32_16x16x32_bf16(Al[mt], Bl[nt], a, 0, 0, 0);
                    acc[mt][nt] = a;
                }
        }
    }
#pragma unroll
    for (int mt = 0; mt < 4; ++mt)
#pragma unroll
        for (int rr = 0; rr < 4; ++rr) {
            int row = n0 + wr * 64 + mt * 16 + quad * 4 + rr;
#pragma unroll
            for (int nt = 0; nt < 4; ++nt) {
                int col = c0 + wc * 64 + nt * 16 + lr;
                size_t o = (size_t)row * 256 + col;
                float v = acc[mt][nt][rr];
                emb[o] = v;
                unsigned short h = f2bf(v);
                eh[o] = h;
                el[o] = f2bf(v - bf2f(h));
            }
        }
    // ---- se partial over this block's 128 cols
    __syncthreads();
    float* sblk = (float*)smemC;       // [2][128]
#pragma unroll
    for (int mt = 0; mt < 4; ++mt)
#pragma unroll
        for (int rr = 0; rr < 4; ++rr) {
            float s = 0.f;
#pragma unroll
            for (int nt = 0; nt < 4; ++nt) {
                float v = acc[mt][nt][rr];
                s = fmaf(v, v, s);
            }
#pragma unroll
            for (int st = 1; st < 16; st <<= 1) s += __shfl_xor(s, st);
            if (lr == 0)
                sblk[wc * 128 + wr * 64 + mt * 16 + quad * 4 + rr] = s;
        }
    __syncthreads();
    if (tid < 128) {
        float* sep = ((bid2 >> 7) == 0) ? se0 : se1;
        sep[n0 + tid] = sblk[tid] + sblk[128 + tid];
    }
}

// ---------------------------------------------------------------- K1:
// Fused bf16x2 (3-term) 16x16x32-MFMA GEMM + argmin.
// mt=4: 64 token rows per wave (A = 256 VGPRs, launch_bounds(256,1) ->
// ~370 VGPR, 1 wave/SIMD, 1 block/CU). Halves LDS-read bytes per MFMA
// (reads/MFMA = 2/(3*mt)) — R7 analysis showed k1 is LDS-read-BW-bound
// (8 waves x 32 KB reads = 3072 cyc/chunk ~= measured 3200).
// Staging/read scheme = R7's coalesced [col][kg^col] XOR layout (R8's
// [kg][col] broke staging coalescence: 64 lines/inst vs 8).
// Grid (NTOK/256, 8 slabs) = 256 blocks = 1/CU.
__global__ __launch_bounds__(256, 1) void k1_dist_argmin(
    const unsigned short* __restrict__ zh, const unsigned short* __restrict__ zl,
    const unsigned short* __restrict__ eh, const unsigned short* __restrict__ el,
    const float* __restrict__ sz, const float* __restrict__ se0,
    const float* __restrict__ se1, float* __restrict__ pval,
    int* __restrict__ pidx) {
    __shared__ short8 smem[2][2048];   // 2 x 32 KB
    const int tid = threadIdx.x;
    const int w = tid >> 6, lane = tid & 63;
    const int quad = lane >> 4, lr = lane & 15;
    const int rowBase = blockIdx.x * 256 + w * 64;
    const int slab = blockIdx.y;
    const int slabBase = slab * 2048;

    // A fragments resident: 4 mt x 8 ks x hi/lo = 256 VGPRs
    short8 Ah[4][8], Al[4][8];
#pragma unroll
    for (int mt = 0; mt < 4; ++mt)
#pragma unroll
        for (int ks = 0; ks < 8; ++ks) {
            size_t o = (size_t)(rowBase + mt * 16 + lr) * 256 + ks * 32 + quad * 8;
            Ah[mt][ks] = *(const short8*)(zh + o);
            Al[mt][ks] = *(const short8*)(zl + o);
        }

    float szr[4][4];
#pragma unroll
    for (int mt = 0; mt < 4; ++mt)
#pragma unroll
        for (int rr = 0; rr < 4; ++rr)
            szr[mt][rr] = sz[rowBase + mt * 16 + quad * 4 + rr];

    float minv[4][4];
    int mini[4][4];
#pragma unroll
    for (int mt = 0; mt < 4; ++mt)
#pragma unroll
        for (int rr = 0; rr < 4; ++rr) {
            minv[mt][rr] = INFINITY;
            mini[mt][rr] = 0;
        }

    // stage chunk `ch` (32 codes x 256 k, hi+lo) into buffer `buf`.
    // LDS unit layout: [fmt][col][kg^col] — consecutive lanes walk kg
    // (XOR-permuted) => two contiguous 512B global slices per inst.
    auto stage = [&](int buf, int ch) {
        const int colBase = slabBase + ch * 32;
#pragma unroll
        for (int i = 0; i < 8; ++i) {
            int u = i * 256 + tid;      // 0..2047
            int fmt = u >> 10;          // wave-uniform
            int u1 = u & 1023;
            int col = u1 >> 5, kgs = u1 & 31;
            int kg = kgs ^ col;         // XOR swizzle
            const unsigned short* g =
                (fmt ? el : eh) + (size_t)(colBase + col) * 256 + kg * 8;
            gload_lds16(g, (char*)&smem[0][0] + buf * 32768 +
                               (((size_t)i * 256 + w * 64) << 4));
        }
    };

    stage(0, 0);
    __syncthreads();

    for (int ch = 0; ch < 64; ++ch) {
        const int cur = ch & 1;
        if (ch + 1 < 64) stage(cur ^ 1, ch + 1);  // async prefetch

        // hoist se loads under the MFMA burst
        const int colg0 = slabBase + ch * 32 + lr;
        const int colg1 = colg0 + 16;
        const float sec0 = se0[colg0] + se1[colg0];
        const float sec1 = se0[colg1] + se1[colg1];

        f32x4v acc[4][2];
#pragma unroll
        for (int mt = 0; mt < 4; ++mt)
#pragma unroll
            for (int nt = 0; nt < 2; ++nt)
                acc[mt][nt] = (f32x4v){0.f, 0.f, 0.f, 0.f};

#pragma unroll
        for (int ks = 0; ks < 8; ++ks) {
            short8 Bh[2], Bl[2];
#pragma unroll
            for (int nt = 0; nt < 2; ++nt) {
                int col = nt * 16 + lr;
                int kgs = (ks * 4 + quad) ^ col;
                Bh[nt] = smem[cur][col * 32 + kgs];
                Bl[nt] = smem[cur][1024 + col * 32 + kgs];
            }
#pragma unroll
            for (int mt = 0; mt < 4; ++mt)
#pragma unroll
                for (int nt = 0; nt < 2; ++nt) {
                    f32x4v a = acc[mt][nt];
                    a = __builtin_amdgcn_mfma_f32_16x16x32_bf16(Ah[mt][ks], Bh[nt], a, 0, 0, 0);
                    a = __builtin_amdgcn_mfma_f32_16x16x32_bf16(Ah[mt][ks], Bl[nt], a, 0, 0, 0);
                    a = __builtin_amdgcn_mfma_f32_16x16x32_bf16(Al[mt][ks], Bh[nt], a, 0, 0, 0);
                    acc[mt][nt] = a;
                }
        }

        // d = fma(-2, dot, fl(sz+se)) == fl(fl(sz+se) - 2*dot) exactly
        const int colBase = slabBase + ch * 32;
#pragma unroll
        for (int nt = 0; nt < 2; ++nt) {
            const int colg = colBase + nt * 16 + lr;
            const float sec = nt ? sec1 : sec0;
#pragma unroll
            for (int mt = 0; mt < 4; ++mt)
#pragma unroll
                for (int rr = 0; rr < 4; ++rr) {
                    float szse = __fadd_rn(szr[mt][rr], sec);
                    float d = fmaf(-2.0f, acc[mt][nt][rr], szse);
                    if (d < minv[mt][rr]) {   // strict <: first index wins
                        minv[mt][rr] = d;
                        mini[mt][rr] = colg;
                    }
                }
        }
        __syncthreads();   // prefetch landed + cur consumed
    }

    // reduce across the 16 lanes (lr) that share each output row
#pragma unroll
    for (int st = 1; st < 16; st <<= 1) {
#pragma unroll
        for (int mt = 0; mt < 4; ++mt)
#pragma unroll
            for (int rr = 0; rr < 4; ++rr) {
                float ov = __shfl_xor(minv[mt][rr], st);
                int oi = __shfl_xor(mini[mt][rr], st);
                if (ov < minv[mt][rr] ||
                    (ov == minv[mt][rr] && oi < mini[mt][rr])) {
                    minv[mt][rr] = ov;
                    mini[mt][rr] = oi;
                }
            }
    }
    if (lr == 0) {
#pragma unroll
        for (int mt = 0; mt < 4; ++mt)
#pragma unroll
            for (int rr = 0; rr < 4; ++rr) {
                int row = rowBase + mt * 16 + quad * 4 + rr;
                pval[(size_t)row * 8 + slab] = minv[mt][rr];
                pidx[(size_t)row * 8 + slab] = mini[mt][rr];
            }
    }
}

// ---------------------------------------------------------------- K3a:
// per-token: reduce 8 slab partials -> final index; rotation scalars;
// per-block loss partial. Reuses sz / se.
__global__ __launch_bounds__(256) void k3a_token(
    const float* __restrict__ z_flat, const float* __restrict__ emb,
    const float* __restrict__ pval, const int* __restrict__ pidx,
    const float* __restrict__ sz, const float* __restrict__ se0,
    const float* __restrict__ se1, float* __restrict__ alpha,
    float* __restrict__ beta, int* __restrict__ idxf,
    float* __restrict__ out, float* __restrict__ lpart) {
    __shared__ float red[4];
    const int w = threadIdx.x >> 6, lane = threadIdx.x & 63;
    const int t = blockIdx.x * 4 + w;

    float bv = INFINITY;
    int bi = 0x7fffffff;
    if (lane < 8) {
        bv = pval[(size_t)t * 8 + lane];
        bi = pidx[(size_t)t * 8 + lane];
    }
#pragma unroll
    for (int st = 1; st < 8; st <<= 1) {
        float ov = __shfl_xor(bv, st);
        int oi = __shfl_xor(bi, st);
        if (ov < bv || (ov == bv && oi < bi)) { bv = ov; bi = oi; }
    }
    const int best = __shfl(bi, 0);

    const float4 zv = *(const float4*)(z_flat + (size_t)t * 256 + lane * 4);
    const float4 ev = *(const float4*)(emb + (size_t)best * 256 + lane * 4);
    float zes = zv.x * ev.x + zv.y * ev.y + zv.z * ev.z + zv.w * ev.w;
#pragma unroll
    for (int m = 1; m < 64; m <<= 1) zes += __shfl_xor(zes, m);

    if (lane == 0) {
        const float szs = sz[t];
        const float ses = se0[best] + se1[best];
        const float sqs = szs + ses - 2.0f * zes;    // loss term (loose tol)
        float ns = sqrtf(szs), nt = sqrtf(ses);
        float inv_s = 1.0f / (ns + EPSV);
        float inv_t = 1.0f / (nt + EPSV);
        float s2 = szs * inv_s;                      // z . u
        float su = szs * inv_s * inv_s;
        float sq = ses * inv_t * inv_t;
        float uq = zes * inv_s * inv_t;
        float nw = sqrtf(su + sq + 2.0f * uq);
        float inv_w = 1.0f / (nw + EPSV);
        float s1 = (s2 + zes * inv_t) * inv_w;       // z . w_
        float scale = nt * inv_s;
        float a = scale * (1.0f - 2.0f * s1 * inv_w * inv_s);
        float bb = scale * inv_t * 2.0f * (s2 - s1 * inv_w);
        alpha[t] = a;
        beta[t] = bb;
        idxf[t] = best;
        out[2097153 + t] = (float)best;
        red[w] = sqs;
    }
    __syncthreads();
    if (threadIdx.x == 0)
        lpart[blockIdx.x] = red[0] + red[1] + red[2] + red[3];
}

// ---------------------------------------------------------------- K3b:
// Tiled z_q: coalesced emb-row gathers + LDS transpose + coalesced writes.
// Grid (128, 4). Block (0,0) also reduces the loss.
__global__ __launch_bounds__(256) void k3b_zq(
    const float* __restrict__ z_flat, const float* __restrict__ emb,
    const float* __restrict__ alpha, const float* __restrict__ beta,
    const int* __restrict__ idxf, const float* __restrict__ lpart,
    float* __restrict__ out) {
    __shared__ float Q[64][65];
    __shared__ float Asm[64], Bsm[64];
    __shared__ int Ism[64];
    const int tid = threadIdx.x;
    const int t0 = blockIdx.x * 64;
    const int c0 = blockIdx.y * 64;

    if (blockIdx.x == 0 && blockIdx.y == 0) {   // ---- loss reduction
        __shared__ float red[4];
        float s = 0.0f;
        for (int i = tid; i < 2048; i += 256) s += lpart[i];
#pragma unroll
        for (int m = 1; m < 64; m <<= 1) s += __shfl_xor(s, m);
        if ((tid & 63) == 0) red[tid >> 6] = s;
        __syncthreads();
        if (tid == 0)
            out[2097152] = 1.25f * (red[0] + red[1] + red[2] + red[3]) *
                           (1.0f / 2097152.0f);
    }

    if (tid < 64) {
        Asm[tid] = alpha[t0 + tid];
        Bsm[tid] = beta[t0 + tid];
        Ism[tid] = idxf[t0 + tid];
    }
    __syncthreads();

    const int sub = tid >> 6, ln = tid & 63;
#pragma unroll
    for (int j = 0; j < 16; ++j) {
        int tl = j * 4 + sub;
        float e = emb[(size_t)Ism[tl] * 256 + c0 + ln];
        float zv = z_flat[(size_t)(t0 + tl) * 256 + c0 + ln];
        Q[tl][ln] = Asm[tl] * zv + Bsm[tl] * e;
    }
    __syncthreads();
    const int b = t0 >> 10, yx0 = t0 & 1023;
#pragma unroll
    for (int j = 0; j < 16; ++j) {
        int cl = j * 4 + sub;
        out[((size_t)(b * 256 + c0 + cl) << 10) + yx0 + ln] = Q[ln][cl];
    }
}

// ----------------------------------------------------------------
extern "C" void kernel_launch(void* const* d_in, const int* in_sizes, int n_in,
                              void* d_out, int out_size, void* d_ws,
                              size_t ws_size, hipStream_t stream) {
    (void)in_sizes; (void)n_in; (void)out_size; (void)ws_size;
    const float* zin = (const float*)d_in[0];
    const float* cb  = (const float*)d_in[1];
    const float* Wm  = (const float*)d_in[2];
    float* out = (float*)d_out;
    char* ws = (char*)d_ws;

    float*          z_flat = (float*)(ws + 0);                     //  8 MB
    unsigned short* zh     = (unsigned short*)(ws + 8388608);      //  4 MB
    unsigned short* zl     = (unsigned short*)(ws + 12582912);     //  4 MB
    float*          emb    = (float*)(ws + 16777216);              // 16 MB
    unsigned short* eh     = (unsigned short*)(ws + 33554432);     //  8 MB
    unsigned short* el     = (unsigned short*)(ws + 41943040);     //  8 MB
    float*          sz     = (float*)(ws + 50331648);              // 32 KB
    float*          se0    = (float*)(ws + 50364416);              // 64 KB
    float*          se1    = (float*)(ws + 50429952);              // 64 KB
    float*          pval   = (float*)(ws + 50495488);              // 256 KB
    int*            pidx   = (int*)(ws + 50757632);                // 256 KB
    float*          alpha  = (float*)(ws + 51019776);              // 32 KB
    float*          beta   = (float*)(ws + 51052544);              // 32 KB
    int*            idxf   = (int*)(ws + 51085312);                // 32 KB
    float*          lpart  = (float*)(ws + 51118080);              //  8 KB

    f0_pre<<<384, 256, 0, stream>>>(zin, z_flat, zh, zl, sz, cb, Wm,
                                    emb, eh, el, se0, se1);
    k1_dist_argmin<<<dim3(32, 8), 256, 0, stream>>>(zh, zl, eh, el, sz,
                                                    se0, se1, pval, pidx);
    k3a_token<<<2048, 256, 0, stream>>>(z_flat, emb, pval, pidx, sz, se0, se1,
                                        alpha, beta, idxf, out, lpart);
    k3b_zq<<<dim3(128, 4), 256, 0, stream>>>(z_flat, emb, alpha, beta, idxf,
                                             lpart, out);
}